// Round 1
// baseline (2367.446 us; speedup 1.0000x reference)
//
#include <hip/hip_runtime.h>
#include <math.h>

#define Cc     8
#define FIELD  7
#define PAD    3
#define TILE   16
#define HALO   (TILE + 2*PAD)   // 22
#define BB     32
#define HH     384
#define WW     384

// u = -log(clip(softmax(x),1e-6,1)) == min(lse(x)-x_c, -log(1e-6))
#define UCLIP 13.815510557964274f

// ---------------- q0 = softmax(x) ----------------
__global__ __launch_bounds__(256)
void init_q(const float* __restrict__ x, float* __restrict__ q) {
    long long p = (long long)blockIdx.x * 256 + threadIdx.x;   // pixel index
    const float4* xp = (const float4*)(x + p * Cc);
    float4 a0 = xp[0], a1 = xp[1];
    float v[Cc] = {a0.x, a0.y, a0.z, a0.w, a1.x, a1.y, a1.z, a1.w};
    float m = v[0];
#pragma unroll
    for (int c = 1; c < Cc; ++c) m = fmaxf(m, v[c]);
    float s = 0.f;
#pragma unroll
    for (int c = 0; c < Cc; ++c) { v[c] = __expf(v[c] - m); s += v[c]; }
    float inv = 1.f / s;
    float4 o0 = make_float4(v[0]*inv, v[1]*inv, v[2]*inv, v[3]*inv);
    float4 o1 = make_float4(v[4]*inv, v[5]*inv, v[6]*inv, v[7]*inv);
    float4* qp = (float4*)(q + p * Cc);
    qp[0] = o0; qp[1] = o1;
}

// ---------------- one mean-field iteration (fused) ----------------
// penalty = conv7x7(qin, masked k) ; t = -(u + penalty) ; o = t @ W + b
// last==0: write softmax(o) (next q); last==1: write o (final logits)
__global__ __launch_bounds__(256)
void mrf_iter(const float* __restrict__ qin,
              const float* __restrict__ x,
              const float* __restrict__ kw,   // [7][7][Cin][Cout] raw (mask applied via skip)
              const float* __restrict__ sw,   // [Cin][Cout] 1x1 mix
              const float* __restrict__ sb,   // [Cout]
              float* __restrict__ out,
              int last)
{
    __shared__ __align__(16) float qs[HALO * HALO * Cc];   // 15488 B

    const int tx = threadIdx.x;            // 0..15
    const int ty = threadIdx.y;            // 0..15
    const int tid = ty * TILE + tx;
    const int w0 = blockIdx.x * TILE;
    const int h0 = blockIdx.y * TILE;
    const int b  = blockIdx.z;

    const float* qb = qin + (long long)b * HH * WW * Cc;

    // --- stage q tile + halo into LDS (zero-pad outside image: SAME padding) ---
    for (int s = tid; s < HALO * HALO; s += 256) {
        int sy = s / HALO, sx = s - sy * HALO;
        int gh = h0 + sy - PAD, gw = w0 + sx - PAD;
        float4 a0, a1;
        if (gh >= 0 && gh < HH && gw >= 0 && gw < WW) {
            const float4* src = (const float4*)(qb + ((long long)gh * WW + gw) * Cc);
            a0 = src[0]; a1 = src[1];
        } else {
            a0 = make_float4(0.f,0.f,0.f,0.f); a1 = a0;
        }
        float4* dst = (float4*)(qs + s * Cc);
        dst[0] = a0; dst[1] = a1;
    }
    __syncthreads();

    // --- 7x7 conv, off-diagonal channel pairs only (diagonal masked => skipped) ---
    float acc[Cc];
#pragma unroll
    for (int c = 0; c < Cc; ++c) acc[c] = 0.f;

    for (int dy = 0; dy < FIELD; ++dy) {
        for (int dx = 0; dx < FIELD; ++dx) {
            const float* qp = qs + ((ty + dy) * HALO + (tx + dx)) * Cc;
            const float* wt = kw + ((dy * FIELD + dx) * Cc) * Cc;  // 64 floats, wave-uniform
            float qv[Cc];
#pragma unroll
            for (int i = 0; i < Cc; ++i) qv[i] = qp[i];
#pragma unroll
            for (int i = 0; i < Cc; ++i) {
#pragma unroll
                for (int c = 0; c < Cc; ++c) {
                    if (c != i)   // 1 - eye mask
                        acc[c] = fmaf(qv[i], wt[i * Cc + c], acc[c]);
                }
            }
        }
    }

    // --- unary potentials recomputed from x: u = min(lse - x, UCLIP) ---
    const long long pix = ((long long)b * HH + (h0 + ty)) * WW + (w0 + tx);
    const float4* xp = (const float4*)(x + pix * Cc);
    float4 x0 = xp[0], x1 = xp[1];
    float xv[Cc] = {x0.x, x0.y, x0.z, x0.w, x1.x, x1.y, x1.z, x1.w};
    float m = xv[0];
#pragma unroll
    for (int c = 1; c < Cc; ++c) m = fmaxf(m, xv[c]);
    float s = 0.f;
#pragma unroll
    for (int c = 0; c < Cc; ++c) s += __expf(xv[c] - m);
    float lse = m + __logf(s);

    float tmix[Cc];
#pragma unroll
    for (int c = 0; c < Cc; ++c) {
        float u = fminf(lse - xv[c], UCLIP);
        tmix[c] = -(u + acc[c]);
    }

    // --- 1x1 channel mix: o[d] = sum_c tmix[c]*sw[c][d] + sb[d] ---
    float o[Cc];
#pragma unroll
    for (int d = 0; d < Cc; ++d) {
        float a = sb[d];
#pragma unroll
        for (int c = 0; c < Cc; ++c) a = fmaf(tmix[c], sw[c * Cc + d], a);
        o[d] = a;
    }

    float* op = out + pix * Cc;
    if (last) {
        float4 o0 = make_float4(o[0], o[1], o[2], o[3]);
        float4 o1 = make_float4(o[4], o[5], o[6], o[7]);
        ((float4*)op)[0] = o0; ((float4*)op)[1] = o1;
    } else {
        float mm = o[0];
#pragma unroll
        for (int d = 1; d < Cc; ++d) mm = fmaxf(mm, o[d]);
        float ss = 0.f;
        float e[Cc];
#pragma unroll
        for (int d = 0; d < Cc; ++d) { e[d] = __expf(o[d] - mm); ss += e[d]; }
        float inv = 1.f / ss;
        float4 o0 = make_float4(e[0]*inv, e[1]*inv, e[2]*inv, e[3]*inv);
        float4 o1 = make_float4(e[4]*inv, e[5]*inv, e[6]*inv, e[7]*inv);
        ((float4*)op)[0] = o0; ((float4*)op)[1] = o1;
    }
}

extern "C" void kernel_launch(void* const* d_in, const int* in_sizes, int n_in,
                              void* d_out, int out_size, void* d_ws, size_t ws_size,
                              hipStream_t stream) {
    (void)in_sizes; (void)n_in; (void)out_size; (void)ws_size;
    const float* x  = (const float*)d_in[0];   // [32,384,384,8]
    const float* kw = (const float*)d_in[1];   // [7,7,8,8]
    const float* sw = (const float*)d_in[2];   // [8,8]
    const float* sb = (const float*)d_in[3];   // [8]
    // d_in[4] = num_iters (==5, compile-time constant here)

    float* qws  = (float*)d_ws;     // 32*384*384*8 floats = 151 MB ping buffer
    float* outp = (float*)d_out;    // pong buffer; final logits land here

    const long long npix = (long long)BB * HH * WW;        // 4,718,592
    init_q<<<(int)(npix / 256), 256, 0, stream>>>(x, qws); // exact multiple

    dim3 grid(WW / TILE, HH / TILE, BB);   // 24 x 24 x 32
    dim3 blk(TILE, TILE);                  // 256 threads

    // 5 iterations, q ping-pongs ws <-> d_out; iter 5 writes logits to d_out
    mrf_iter<<<grid, blk, 0, stream>>>(qws,  x, kw, sw, sb, outp, 0);
    mrf_iter<<<grid, blk, 0, stream>>>(outp, x, kw, sw, sb, qws,  0);
    mrf_iter<<<grid, blk, 0, stream>>>(qws,  x, kw, sw, sb, outp, 0);
    mrf_iter<<<grid, blk, 0, stream>>>(outp, x, kw, sw, sb, qws,  0);
    mrf_iter<<<grid, blk, 0, stream>>>(qws,  x, kw, sw, sb, outp, 1);
}

// Round 2
// 724.893 us; speedup vs baseline: 3.2659x; 3.2659x over previous
//
#include <hip/hip_runtime.h>
#include <math.h>

#define Cc     8
#define FIELD  7
#define NTAP   49        // 7*7
#define PAD    3
#define TILE   16
#define HALO   22        // TILE + 2*PAD
#define BB     32
#define HH     384
#define WW     384
#define NJ     13        // ceil(49/4) MFMAs of K=32 (4 taps each); 52 tap slots
#define UCLIP  13.815510557964274f   // -log(1e-6)

typedef __attribute__((ext_vector_type(8))) short short8;  // 8 bf16 = 4 VGPRs
typedef __attribute__((ext_vector_type(4))) float f32x4;   // MFMA C/D

__device__ __forceinline__ unsigned short f2bf(float f) {   // RNE fp32->bf16
    unsigned u = __float_as_uint(f);
    u += 0x7FFFu + ((u >> 16) & 1u);
    return (unsigned short)(u >> 16);
}

// ---------------------------------------------------------------------------
// prep_w: wtab[tap][n][j] (bf16) = sum_cout kw[tap][j][cout]*(cout!=j)*sw[cout][n]
// tap in [0,52): taps 49..51 are zero pads; n in [0,16): n>=8 zero pads.
// Layout chosen so a B-fragment lane (n=lane&15, g=lane>>4) reads its 8
// contiguous j-elements as one dwordx4.
// ---------------------------------------------------------------------------
__global__ __launch_bounds__(256)
void prep_w(const float* __restrict__ kw, const float* __restrict__ sw,
            unsigned short* __restrict__ wtab) {
    int it = blockIdx.x * 256 + threadIdx.x;      // (tap, j=cin)
    if (it >= 52 * 8) return;
    int tap = it >> 3, j = it & 7;
    float kv[Cc];
#pragma unroll
    for (int c = 0; c < Cc; ++c)
        kv[c] = (tap < NTAP) ? kw[((tap)*Cc + j) * Cc + c] : 0.f;
    kv[j] = 0.f;                                   // (1 - eye) mask on (cin,cout)
#pragma unroll
    for (int n = 0; n < 16; ++n) {
        float a = 0.f;
        if (n < Cc) {
#pragma unroll
            for (int c = 0; c < Cc; ++c) a = fmaf(kv[c], sw[c * Cc + n], a);
        }
        wtab[(tap * 16 + n) * 8 + j] = f2bf(a);
    }
}

// ---------------------------------------------------------------------------
// init_qv: q0 = softmax(x) packed bf16x8; v = b - u@W  (u = min(lse-x, UCLIP))
// ---------------------------------------------------------------------------
__global__ __launch_bounds__(256)
void init_qv(const float* __restrict__ x, const float* __restrict__ sw,
             const float* __restrict__ sb,
             uint4* __restrict__ q0, float* __restrict__ v) {
    long long p = (long long)blockIdx.x * 256 + threadIdx.x;
    const float4* xp = (const float4*)(x + p * Cc);
    float4 a0 = xp[0], a1 = xp[1];
    float xv[Cc] = {a0.x, a0.y, a0.z, a0.w, a1.x, a1.y, a1.z, a1.w};
    float m = xv[0];
#pragma unroll
    for (int c = 1; c < Cc; ++c) m = fmaxf(m, xv[c]);
    float s = 0.f, e[Cc];
#pragma unroll
    for (int c = 0; c < Cc; ++c) { e[c] = __expf(xv[c] - m); s += e[c]; }
    float inv = 1.f / s;
    uint4 qo;
    qo.x = f2bf(e[0] * inv) | ((unsigned)f2bf(e[1] * inv) << 16);
    qo.y = f2bf(e[2] * inv) | ((unsigned)f2bf(e[3] * inv) << 16);
    qo.z = f2bf(e[4] * inv) | ((unsigned)f2bf(e[5] * inv) << 16);
    qo.w = f2bf(e[6] * inv) | ((unsigned)f2bf(e[7] * inv) << 16);
    q0[p] = qo;

    float lse = m + __logf(s);
    float u[Cc];
#pragma unroll
    for (int c = 0; c < Cc; ++c) u[c] = fminf(lse - xv[c], UCLIP);
    float vv[Cc];
#pragma unroll
    for (int d = 0; d < Cc; ++d) {
        float a = sb[d];
#pragma unroll
        for (int c = 0; c < Cc; ++c) a = fmaf(-u[c], sw[c * Cc + d], a);
        vv[d] = a;
    }
    float4* vp = (float4*)(v + p * Cc);
    vp[0] = make_float4(vv[0], vv[1], vv[2], vv[3]);
    vp[1] = make_float4(vv[4], vv[5], vv[6], vv[7]);
}

// ---------------------------------------------------------------------------
// mrf_iter: logits = v - conv7x7(q, k'); out = softmax(logits) bf16 (or
// logits fp32 on the last iteration). Conv via mfma_f32_16x16x32_bf16:
// M=16 pixels (a row of the tile), N=16 (8 real out channels), K=32 = 4 taps.
// Block = 256 threads = 4 waves; wave w owns tile rows 4w..4w+3.
// ---------------------------------------------------------------------------
__global__ __launch_bounds__(256)
void mrf_iter(const uint4* __restrict__ qin,          // bf16x8 per pixel
              const unsigned short* __restrict__ wtab,
              const float* __restrict__ v,            // fp32, 8 per pixel
              uint4* __restrict__ qout,               // next q (bf16) if !last
              float* __restrict__ lout,               // logits fp32 if last
              int last) {
    __shared__ __align__(16) uint4 qs[HALO * HALO];     // 7744 B, bf16x8/pixel
    __shared__ __align__(16) float pen[TILE * TILE * Cc]; // 8192 B

    const int tid = threadIdx.x;
    const int wv  = tid >> 6;        // wave 0..3
    const int l   = tid & 63;
    const int m   = l & 15;          // A-row = px;  also D-col = n
    const int g   = l >> 4;          // K-group: tap 4J+g

    const int w0 = blockIdx.x * TILE;
    const int h0 = blockIdx.y * TILE;
    const int b  = blockIdx.z;

    // --- B fragments: 13 x (8 bf16) from the precomputed k' table (L2-hot) ---
    short8 bw[NJ];
#pragma unroll
    for (int J = 0; J < NJ; ++J) {
        int tap = 4 * J + g;
        uint4 t = *(const uint4*)(wtab + (tap * 16 + m) * 8);
        bw[J] = __builtin_bit_cast(short8, t);
    }

    // --- stage q tile + halo (bf16x8 per pixel, zero-pad = SAME) ---
    const uint4* qb = qin + (long long)b * HH * WW;
    for (int s = tid; s < HALO * HALO; s += 256) {
        int sy = s / HALO, sx = s - sy * HALO;
        int gh = h0 + sy - PAD, gw = w0 + sx - PAD;
        uint4 val = make_uint4(0, 0, 0, 0);
        if (gh >= 0 && gh < HH && gw >= 0 && gw < WW)
            val = qb[(long long)gh * WW + gw];
        qs[s] = val;
    }
    __syncthreads();

    // --- K loop: 13 MFMAs x 4 row-tiles ---
    f32x4 acc[4];
#pragma unroll
    for (int r = 0; r < 4; ++r) acc[r] = (f32x4){0.f, 0.f, 0.f, 0.f};

    const int rowbase = 4 * wv;
#pragma unroll
    for (int J = 0; J < NJ; ++J) {
        int tap = 4 * J + g;
        if (tap > 48) tap = 48;              // address clamp; weight is 0 there
        int dy = tap / 7, dx = tap - dy * 7;
        int e0 = dy * HALO + m + dx;         // entry index at tile row 0
#pragma unroll
        for (int r = 0; r < 4; ++r) {
            short8 a = *(const short8*)&qs[e0 + (rowbase + r) * HALO];
            acc[r] = __builtin_amdgcn_mfma_f32_16x16x32_bf16(a, bw[J], acc[r], 0, 0, 0);
        }
    }

    // --- scatter D to LDS: lane(reg t) holds D[px=g*4+t][n=m] for row 4wv+r ---
    if (m < Cc) {
#pragma unroll
        for (int r = 0; r < 4; ++r) {
            int py = rowbase + r;
#pragma unroll
            for (int t = 0; t < 4; ++t)
                pen[((py * TILE) + (g * 4 + t)) * Cc + m] = acc[r][t];
        }
    }
    __syncthreads();

    // --- epilogue: one thread per pixel ---
    const int px = tid & 15, py = tid >> 4;
    const long long pix = ((long long)b * HH + (h0 + py)) * WW + (w0 + px);
    const float4* pp = (const float4*)&pen[tid * Cc];
    float4 p0 = pp[0], p1 = pp[1];
    const float4* vp = (const float4*)(v + pix * Cc);
    float4 v0 = vp[0], v1 = vp[1];
    float o[Cc] = {v0.x - p0.x, v0.y - p0.y, v0.z - p0.z, v0.w - p0.w,
                   v1.x - p1.x, v1.y - p1.y, v1.z - p1.z, v1.w - p1.w};
    if (last) {
        float4* op = (float4*)(lout + pix * Cc);
        op[0] = make_float4(o[0], o[1], o[2], o[3]);
        op[1] = make_float4(o[4], o[5], o[6], o[7]);
    } else {
        float mm = o[0];
#pragma unroll
        for (int d = 1; d < Cc; ++d) mm = fmaxf(mm, o[d]);
        float ss = 0.f, e[Cc];
#pragma unroll
        for (int d = 0; d < Cc; ++d) { e[d] = __expf(o[d] - mm); ss += e[d]; }
        float inv = 1.f / ss;
        uint4 qo;
        qo.x = f2bf(e[0] * inv) | ((unsigned)f2bf(e[1] * inv) << 16);
        qo.y = f2bf(e[2] * inv) | ((unsigned)f2bf(e[3] * inv) << 16);
        qo.z = f2bf(e[4] * inv) | ((unsigned)f2bf(e[5] * inv) << 16);
        qo.w = f2bf(e[6] * inv) | ((unsigned)f2bf(e[7] * inv) << 16);
        qout[pix] = qo;
    }
}

extern "C" void kernel_launch(void* const* d_in, const int* in_sizes, int n_in,
                              void* d_out, int out_size, void* d_ws, size_t ws_size,
                              hipStream_t stream) {
    (void)in_sizes; (void)n_in; (void)out_size; (void)ws_size;
    const float* x  = (const float*)d_in[0];   // [32,384,384,8]
    const float* kw = (const float*)d_in[1];   // [7,7,8,8]
    const float* sw = (const float*)d_in[2];   // [8,8]
    const float* sb = (const float*)d_in[3];   // [8]

    const size_t QSZ = (size_t)BB * HH * WW * 16;        // 75,497,472 B (bf16x8)
    uint4* qA = (uint4*)d_ws;
    uint4* qB = (uint4*)((char*)d_ws + QSZ);
    unsigned short* wt = (unsigned short*)((char*)d_ws + 2 * QSZ);  // 13312 B
    float* vbuf = (float*)d_out;   // v lives in d_out; last iter overwrites in place

    prep_w<<<2, 256, 0, stream>>>(kw, sw, wt);

    const long long npix = (long long)BB * HH * WW;
    init_qv<<<(int)(npix / 256), 256, 0, stream>>>(x, sw, sb, qA, vbuf);

    dim3 grid(WW / TILE, HH / TILE, BB);   // 24 x 24 x 32
    mrf_iter<<<grid, 256, 0, stream>>>(qA, wt, vbuf, qB, nullptr, 0);
    mrf_iter<<<grid, 256, 0, stream>>>(qB, wt, vbuf, qA, nullptr, 0);
    mrf_iter<<<grid, 256, 0, stream>>>(qA, wt, vbuf, qB, nullptr, 0);
    mrf_iter<<<grid, 256, 0, stream>>>(qB, wt, vbuf, qA, nullptr, 0);
    mrf_iter<<<grid, 256, 0, stream>>>(qA, wt, vbuf, nullptr, (float*)d_out, 1);
}